// Round 3
// baseline (157.168 us; speedup 1.0000x reference)
//
#include <hip/hip_runtime.h>

// CurvatureLoss: B=4, N=4096, fp32.
// R10: R9 fixed the scratch/LDS blowup and cut issued VALU ~12%, but time was
// flat: grid shrank to 1024x4-wave blocks -> 4 blocks/CU, Occupancy 52->29%,
// VALUBusy 96->79% (savings became stalls). Work is fixed at 4096 waves, so
// restore packing granularity instead: 128-thread blocks (2 waves, QPB=8,
// NBLK=2048 like R7) + prefetch distance 4 (unroll 4, renamed rotations) to
// cover L2 latency at ~4 waves/SIMD. Inner loop identical to R9 (QPW=4,
// top-2 + self-zap, embed6/ballot recovery, pointer-free epilogue).

constexpr int BB   = 4;
constexpr int NN   = 4096;
constexpr int QPW  = 4;              // queries per wave
constexpr int WPB  = 2;              // waves per block
constexpr int QPB  = WPB * QPW;      // 8 queries per block
constexpr int CPB  = 64;             // chunk = lane
constexpr int NK   = NN / CPB;       // 64 steps; candidate j = 64*k + lane
constexpr int NBLK = BB * NN / QPB;  // 2048 blocks
constexpr float NEGBIG = -3.402823466e+38f;

__global__ __launch_bounds__(256) void pack_kernel(
    const float* __restrict__ ori, const float* __restrict__ adv,
    float4* __restrict__ oriP, float4* __restrict__ advP)
{
    const int i = blockIdx.x * blockDim.x + threadIdx.x;
    if (i < BB * NN) {
        float x = ori[3 * i], y = ori[3 * i + 1], z = ori[3 * i + 2];
        oriP[i] = make_float4(x, y, z, 0.5f * (x * x + y * y + z * z));
        x = adv[3 * i]; y = adv[3 * i + 1]; z = adv[3 * i + 2];
        advP[i] = make_float4(x, y, z, 0.5f * (x * x + y * y + z * z));
    }
}

__device__ __forceinline__ float embed6(float t, unsigned eb) {
    return __uint_as_float((__float_as_uint(t) & 0xFFFFFFC0u) | eb);  // v_and_or_b32
}

__device__ __forceinline__ float fmed3(float a, float b, float c) {
    return __builtin_amdgcn_fmed3f(a, b, c);
}

// v: merged key; p0/p1: this lane's partials. Wave-uniform result.
// Lowest matching lane = smallest global index (j = 64k + lane).
__device__ __forceinline__ int recover_j(float v, float p0, float p1) {
    unsigned long long m = __ballot((p0 == v) || (p1 == v));
    const int lane = (int)__ffsll(m) - 1;
    const int k = (NK - 1) - (int)(__float_as_uint(v) & (unsigned)(NK - 1));
    return (k << 6) | lane;
}

__device__ __forceinline__ float unit_absdot4(const float4* __restrict__ pc, int i,
                                              float px, float py, float pz,
                                              float nx, float ny, float nz) {
    const float4 c = pc[i];
    const float vx = c.x - px, vy = c.y - py, vz = c.z - pz;
    const float s  = vx * vx + vy * vy + vz * vz + 1e-12f;
    return fabsf((vx * nx + vy * ny + vz * nz) * (1.0f / sqrtf(s)));
}

__global__ __launch_bounds__(128, 4) void knn_kernel(
    const float4* __restrict__ oriP, const float4* __restrict__ advP,
    const float* __restrict__ nrm, float* __restrict__ partial,
    float* __restrict__ out, int use_partial)
{
    const int tid = threadIdx.x;
    const int ch  = tid & 63;          // chunk = lane
    const int qs  = tid >> 6;          // wave id 0..1
    const int b   = blockIdx.x >> 9;   // / (N/QPB = 512)
    const int qt  = blockIdx.x & 511;
    const int qb  = qt * QPB + qs * QPW;   // first query of this wave

    const float4* __restrict__ ob = oriP + (size_t)b * NN;
    const float4* __restrict__ ab = advP + (size_t)b * NN;
    const float*  __restrict__ nb = nrm  + (size_t)b * NN * 3;

    float4 qo[QPW], qa[QPW];
    #pragma unroll
    for (int i = 0; i < QPW; ++i) { qo[i] = ob[qb + i]; qa[i] = ab[qb + i]; }

    // top-2 trackers (max = closest); self is zapped at its (uniform) step.
    float oA[QPW], oB[QPW], aA[QPW], aB[QPW], mm[QPW];
    #pragma unroll
    for (int i = 0; i < QPW; ++i) {
        oA[i] = NEGBIG; oB[i] = NEGBIG;
        aA[i] = NEGBIG; aB[i] = NEGBIG;
        mm[i] = NEGBIG;
    }

    const int kself = qb >> 6;         // all 4 queries share one self step
    const int sl    = qb & 63;         // self lanes sl..sl+3

    const float4* __restrict__ op = ob + ch;
    const float4* __restrict__ ap = ab + ch;

    // one step: 12 dots (3 matrices x 4 queries) + top-2/argmax updates
    auto stepf = [&](const float4& co, const float4& ca, unsigned eb, bool selfstep) {
        float ko[QPW], ka[QPW], km[QPW];
        #pragma unroll
        for (int i = 0; i < QPW; ++i) {
            float t;
            t = fmaf(qo[i].z, co.z, -co.w); t = fmaf(qo[i].y, co.y, t); t = fmaf(qo[i].x, co.x, t);
            ko[i] = embed6(t, eb);
            t = fmaf(qa[i].z, co.z, -co.w); t = fmaf(qa[i].y, co.y, t); t = fmaf(qa[i].x, co.x, t);
            km[i] = embed6(t, eb);
            t = fmaf(qa[i].z, ca.z, -ca.w); t = fmaf(qa[i].y, ca.y, t); t = fmaf(qa[i].x, ca.x, t);
            ka[i] = embed6(t, eb);
        }
        if (selfstep) {                 // wave-uniform branch, taken once in 64
            #pragma unroll
            for (int i = 0; i < QPW; ++i) {
                const bool s = (ch == sl + i);
                ko[i] = s ? NEGBIG : ko[i];   // self excluded from ori-ori
                ka[i] = s ? NEGBIG : ka[i];   // self excluded from adv-adv
                // km (adv->ori argmax) keeps self: ref argmin is over ALL ori
            }
        }
        #pragma unroll
        for (int i = 0; i < QPW; ++i) {
            oB[i] = fmed3(oA[i], oB[i], ko[i]); oA[i] = fmaxf(oA[i], ko[i]);
            aB[i] = fmed3(aA[i], aB[i], ka[i]); aA[i] = fmaxf(aA[i], ka[i]);
            mm[i] = fmaxf(mm[i], km[i]);
        }
    };

    // software pipeline, prefetch distance 4; rotations become renames
    // under unroll 4; last 4 steps peeled (no OOB prefetch).
    float4 p0o = op[0 * CPB], p0a = ap[0 * CPB];
    float4 p1o = op[1 * CPB], p1a = ap[1 * CPB];
    float4 p2o = op[2 * CPB], p2a = ap[2 * CPB];
    float4 p3o = op[3 * CPB], p3a = ap[3 * CPB];

    #pragma unroll 4
    for (int k = 0; k < NK - 4; ++k) {
        const float4 no = op[(k + 4) * CPB];
        const float4 na = ap[(k + 4) * CPB];
        stepf(p0o, p0a, (unsigned)(NK - 1 - k), k == kself);
        p0o = p1o; p0a = p1a;
        p1o = p2o; p1a = p2a;
        p2o = p3o; p2a = p3a;
        p3o = no;  p3a = na;
    }
    stepf(p0o, p0a, 3u, (NK - 4) == kself);
    stepf(p1o, p1a, 2u, (NK - 3) == kself);
    stepf(p2o, p2a, 1u, (NK - 2) == kself);
    stepf(p3o, p3a, 0u, (NK - 1) == kself);

    // save per-lane partials for index recovery
    float soA[QPW], soB[QPW], saA[QPW], saB[QPW], sm[QPW];
    #pragma unroll
    for (int i = 0; i < QPW; ++i) {
        soA[i] = oA[i]; soB[i] = oB[i];
        saA[i] = aA[i]; saB[i] = aB[i];
        sm[i]  = mm[i];
    }

    // wave butterfly top-2 merge: A=max(a0,b0); B=max(min(a0,b0),max(a1,b1))
    #pragma unroll
    for (int off = 1; off < 64; off <<= 1) {
        #pragma unroll
        for (int i = 0; i < QPW; ++i) {
            float r0, r1, mn;
            r0 = __shfl_xor(oA[i], off); r1 = __shfl_xor(oB[i], off);
            mn = fminf(oA[i], r0); oA[i] = fmaxf(oA[i], r0); oB[i] = fmaxf(mn, fmaxf(oB[i], r1));
            r0 = __shfl_xor(aA[i], off); r1 = __shfl_xor(aB[i], off);
            mn = fminf(aA[i], r0); aA[i] = fmaxf(aA[i], r0); aB[i] = fmaxf(mn, fmaxf(aB[i], r1));
            mm[i] = fmaxf(mm[i], __shfl_xor(mm[i], off));
        }
    }

    // recover global candidate indices (wave-uniform, ballot-based)
    int jo0[QPW], jo1[QPW], ja0[QPW], ja1[QPW], jm[QPW];
    #pragma unroll
    for (int i = 0; i < QPW; ++i) {
        jo0[i] = recover_j(oA[i], soA[i], soB[i]);
        jo1[i] = recover_j(oB[i], soA[i], soB[i]);
        ja0[i] = recover_j(aA[i], saA[i], saB[i]);
        ja1[i] = recover_j(aB[i], saA[i], saB[i]);
        jm[i]  = recover_j(mm[i], sm[i], sm[i]);
    }

    float val = 0.0f;
    if (ch < QPW) {                     // lane i -> query qb+i
        // pointer-free, constant-index selection (keeps arrays SROA-able)
        int io0 = jo0[0], io1 = jo1[0], ia0 = ja0[0], ia1 = ja1[0], im = jm[0];
        float4 qoS = qo[0], qaS = qa[0];
        #pragma unroll
        for (int i = 1; i < QPW; ++i) {
            if (ch == i) {
                io0 = jo0[i]; io1 = jo1[i];
                ia0 = ja0[i]; ia1 = ja1[i];
                im  = jm[i];
                qoS = qo[i];  qaS = qa[i];
            }
        }
        const int q = qb + ch;

        const float nx = nb[3 * q], ny = nb[3 * q + 1], nz = nb[3 * q + 2];
        const float ok = 0.5f * (unit_absdot4(ob, io0, qoS.x, qoS.y, qoS.z, nx, ny, nz) +
                                 unit_absdot4(ob, io1, qoS.x, qoS.y, qoS.z, nx, ny, nz));
        const float ax = nb[3 * im], ay = nb[3 * im + 1], az = nb[3 * im + 2];
        const float ak = 0.5f * (unit_absdot4(ab, ia0, qaS.x, qaS.y, qaS.z, ax, ay, az) +
                                 unit_absdot4(ab, ia1, qaS.x, qaS.y, qaS.z, ax, ay, az));
        const float d = ak - ok;
        val = d * d;
    }
    val += __shfl_down(val, 2);         // lanes 0..3 -> lane 0
    val += __shfl_down(val, 1);

    __shared__ float sval[WPB];
    if (ch == 0) sval[qs] = val;
    __syncthreads();
    if (tid == 0) {
        const float s = sval[0] + sval[1];
        if (use_partial) partial[blockIdx.x] = s;
        else             atomicAdd(out, s * (1.0f / (float)(BB * NN)));
    }
}

__global__ __launch_bounds__(256) void reduce_kernel(
    const float* __restrict__ partial, float* __restrict__ out)
{
    const int tid = threadIdx.x;
    float s = 0.0f;
    #pragma unroll
    for (int i = tid; i < NBLK; i += 256) s += partial[i];
    #pragma unroll
    for (int off = 32; off > 0; off >>= 1) s += __shfl_down(s, off);
    __shared__ float ls[4];
    if ((tid & 63) == 0) ls[tid >> 6] = s;
    __syncthreads();
    if (tid == 0)
        out[0] = (ls[0] + ls[1] + ls[2] + ls[3]) * (1.0f / (float)(BB * NN));
}

extern "C" void kernel_launch(void* const* d_in, const int* in_sizes, int n_in,
                              void* d_out, int out_size, void* d_ws, size_t ws_size,
                              hipStream_t stream) {
    const float* ori = (const float*)d_in[0];
    const float* adv = (const float*)d_in[1];
    const float* nrm = (const float*)d_in[2];
    float* out = (float*)d_out;

    float4* oriP = (float4*)d_ws;                    // 256 KB
    float4* advP = oriP + (size_t)BB * NN;           // 256 KB
    float*  part = (float*)(advP + (size_t)BB * NN); // 8 KB
    const size_t need = (size_t)2 * BB * NN * sizeof(float4) + NBLK * sizeof(float);
    const int use_partial = (ws_size >= need) ? 1 : 0;

    if (!use_partial)
        hipMemsetAsync(out, 0, sizeof(float), stream);

    hipLaunchKernelGGL(pack_kernel, dim3((BB * NN + 255) / 256), dim3(256), 0, stream,
                       ori, adv, oriP, advP);
    hipLaunchKernelGGL(knn_kernel, dim3(NBLK), dim3(128), 0, stream,
                       oriP, advP, nrm, part, out, use_partial);
    if (use_partial)
        hipLaunchKernelGGL(reduce_kernel, dim3(1), dim3(256), 0, stream, part, out);
}

// Round 4
// 111.698 us; speedup vs baseline: 1.4071x; 1.4071x over previous
//
#include <hip/hip_runtime.h>

// CurvatureLoss: B=4, N=4096, fp32.
// R11: R10's distance-4 pipeline spilled (WRITE_SIZE 143MB) -> revert to the
// verified distance-2/QPW=4 loop (R9, VGPR=64 clean). R9's remaining problem
// was wave count (4096 waves -> VALUBusy 79%). Fix: split the candidate axis.
// Block = 4 waves = 2 query-groups x 2 candidate-halves; each wave runs the
// R9 loop over 32 of 64 steps -> 8192 waves (R7 packing) at R9 instruction
// count. Halves merge top-2 via 320B LDS (embed-bit ranges disjoint across
// halves, so max-merge is exact); index recovery per-wave via ballot (-1 in
// the non-owning half), max-combined through LDS.

constexpr int BB   = 4;
constexpr int NN   = 4096;
constexpr int QPW  = 4;              // queries per wave
constexpr int GPB  = 2;              // query groups per block
constexpr int QPB  = GPB * QPW;      // 8 queries per block
constexpr int CPB  = 64;             // chunk = lane
constexpr int NK   = NN / CPB;       // 64 global steps; candidate j = 64*k + lane
constexpr int NKH  = NK / 2;         // 32 steps per wave (half)
constexpr int NBLK = BB * NN / QPB;  // 2048 blocks
constexpr float NEGBIG = -3.402823466e+38f;

__global__ __launch_bounds__(256) void pack_kernel(
    const float* __restrict__ ori, const float* __restrict__ adv,
    float4* __restrict__ oriP, float4* __restrict__ advP)
{
    const int i = blockIdx.x * blockDim.x + threadIdx.x;
    if (i < BB * NN) {
        float x = ori[3 * i], y = ori[3 * i + 1], z = ori[3 * i + 2];
        oriP[i] = make_float4(x, y, z, 0.5f * (x * x + y * y + z * z));
        x = adv[3 * i]; y = adv[3 * i + 1]; z = adv[3 * i + 2];
        advP[i] = make_float4(x, y, z, 0.5f * (x * x + y * y + z * z));
    }
}

__device__ __forceinline__ float embed6(float t, unsigned eb) {
    return __uint_as_float((__float_as_uint(t) & 0xFFFFFFC0u) | eb);  // v_and_or_b32
}

__device__ __forceinline__ float fmed3(float a, float b, float c) {
    return __builtin_amdgcn_fmed3f(a, b, c);
}

// v: merged key; p0/p1: this lane's partials. Wave-uniform result.
// Lowest matching lane = smallest global index (j = 64k + lane).
// If no lane of this wave produced v, returns -1 ((k<<6) | -1 == -1).
__device__ __forceinline__ int recover_j(float v, float p0, float p1) {
    unsigned long long m = __ballot((p0 == v) || (p1 == v));
    const int lane = (int)__ffsll(m) - 1;
    const int k = (NK - 1) - (int)(__float_as_uint(v) & (unsigned)(NK - 1));
    return (k << 6) | lane;
}

__device__ __forceinline__ float unit_absdot4(const float4* __restrict__ pc, int i,
                                              float px, float py, float pz,
                                              float nx, float ny, float nz) {
    const float4 c = pc[i];
    const float vx = c.x - px, vy = c.y - py, vz = c.z - pz;
    const float s  = vx * vx + vy * vy + vz * vz + 1e-12f;
    return fabsf((vx * nx + vy * ny + vz * nz) * (1.0f / sqrtf(s)));
}

__global__ __launch_bounds__(256, 4) void knn_kernel(
    const float4* __restrict__ oriP, const float4* __restrict__ advP,
    const float* __restrict__ nrm, float* __restrict__ partial,
    float* __restrict__ out, int use_partial)
{
    const int tid = threadIdx.x;
    const int ch  = tid & 63;          // chunk = lane
    const int qs  = tid >> 6;          // wave id 0..3
    const int g   = qs >> 1;           // query group 0..1
    const int h   = qs & 1;            // candidate half 0..1
    const int b   = blockIdx.x >> 9;   // / (N/QPB = 512)
    const int qt  = blockIdx.x & 511;
    const int qb  = qt * QPB + g * QPW;    // first query of this group

    const float4* __restrict__ ob = oriP + (size_t)b * NN;
    const float4* __restrict__ ab = advP + (size_t)b * NN;
    const float*  __restrict__ nb = nrm  + (size_t)b * NN * 3;

    float4 qo[QPW], qa[QPW];
    #pragma unroll
    for (int i = 0; i < QPW; ++i) { qo[i] = ob[qb + i]; qa[i] = ab[qb + i]; }

    // top-2 trackers (max = closest); self is zapped at its (uniform) step.
    float oA[QPW], oB[QPW], aA[QPW], aB[QPW], mm[QPW];
    #pragma unroll
    for (int i = 0; i < QPW; ++i) {
        oA[i] = NEGBIG; oB[i] = NEGBIG;
        aA[i] = NEGBIG; aB[i] = NEGBIG;
        mm[i] = NEGBIG;
    }

    const int kself = qb >> 6;         // all 4 queries share one self step
    const int sl    = qb & 63;         // self lanes sl..sl+3

    const float4* __restrict__ op = ob + ch + (size_t)h * NKH * CPB;
    const float4* __restrict__ ap = ab + ch + (size_t)h * NKH * CPB;

    // one step: 12 dots (3 matrices x 4 queries) + top-2/argmax updates
    auto stepf = [&](const float4& co, const float4& ca, unsigned eb, bool selfstep) {
        float ko[QPW], ka[QPW], km[QPW];
        #pragma unroll
        for (int i = 0; i < QPW; ++i) {
            float t;
            t = fmaf(qo[i].z, co.z, -co.w); t = fmaf(qo[i].y, co.y, t); t = fmaf(qo[i].x, co.x, t);
            ko[i] = embed6(t, eb);
            t = fmaf(qa[i].z, co.z, -co.w); t = fmaf(qa[i].y, co.y, t); t = fmaf(qa[i].x, co.x, t);
            km[i] = embed6(t, eb);
            t = fmaf(qa[i].z, ca.z, -ca.w); t = fmaf(qa[i].y, ca.y, t); t = fmaf(qa[i].x, ca.x, t);
            ka[i] = embed6(t, eb);
        }
        if (selfstep) {                 // wave-uniform branch, taken <= once per wave
            #pragma unroll
            for (int i = 0; i < QPW; ++i) {
                const bool s = (ch == sl + i);
                ko[i] = s ? NEGBIG : ko[i];   // self excluded from ori-ori
                ka[i] = s ? NEGBIG : ka[i];   // self excluded from adv-adv
                // km (adv->ori argmax) keeps self: ref argmin is over ALL ori
            }
        }
        #pragma unroll
        for (int i = 0; i < QPW; ++i) {
            oB[i] = fmed3(oA[i], oB[i], ko[i]); oA[i] = fmaxf(oA[i], ko[i]);
            aB[i] = fmed3(aA[i], aB[i], ka[i]); aA[i] = fmaxf(aA[i], ka[i]);
            mm[i] = fmaxf(mm[i], km[i]);
        }
    };

    // software pipeline, prefetch distance 2 (verified no-spill config);
    // this wave covers global steps kg in [h*NKH, h*NKH+NKH).
    const int kg0 = h * NKH;
    float4 c0o = op[0 * CPB], c0a = ap[0 * CPB];
    float4 c1o = op[1 * CPB], c1a = ap[1 * CPB];

    #pragma unroll 2
    for (int k = 0; k < NKH - 2; ++k) {
        const float4 c2o = op[(k + 2) * CPB];
        const float4 c2a = ap[(k + 2) * CPB];
        const int kg = kg0 + k;
        stepf(c0o, c0a, (unsigned)(NK - 1 - kg), kg == kself);
        c0o = c1o; c0a = c1a;
        c1o = c2o; c1a = c2a;
    }
    stepf(c0o, c0a, (unsigned)(NK - 1 - (kg0 + NKH - 2)), (kg0 + NKH - 2) == kself);
    stepf(c1o, c1a, (unsigned)(NK - 1 - (kg0 + NKH - 1)), (kg0 + NKH - 1) == kself);

    // save per-lane partials for index recovery
    float soA[QPW], soB[QPW], saA[QPW], saB[QPW], sm[QPW];
    #pragma unroll
    for (int i = 0; i < QPW; ++i) {
        soA[i] = oA[i]; soB[i] = oB[i];
        saA[i] = aA[i]; saB[i] = aB[i];
        sm[i]  = mm[i];
    }

    // wave butterfly top-2 merge: A=max(a0,b0); B=max(min(a0,b0),max(a1,b1))
    #pragma unroll
    for (int off = 1; off < 64; off <<= 1) {
        #pragma unroll
        for (int i = 0; i < QPW; ++i) {
            float r0, r1, mn;
            r0 = __shfl_xor(oA[i], off); r1 = __shfl_xor(oB[i], off);
            mn = fminf(oA[i], r0); oA[i] = fmaxf(oA[i], r0); oB[i] = fmaxf(mn, fmaxf(oB[i], r1));
            r0 = __shfl_xor(aA[i], off); r1 = __shfl_xor(aB[i], off);
            mn = fminf(aA[i], r0); aA[i] = fmaxf(aA[i], r0); aB[i] = fmaxf(mn, fmaxf(aB[i], r1));
            mm[i] = fmaxf(mm[i], __shfl_xor(mm[i], off));
        }
    }

    // cross-half value exchange + top-2 merge (keys are wave-uniform now).
    // Halves generate disjoint embed-bit ranges -> no cross-half ties.
    __shared__ float vbuf[GPB][2][5 * QPW];
    __shared__ int   jbuf[GPB][2][5 * QPW];
    if (ch == 0) {
        #pragma unroll
        for (int i = 0; i < QPW; ++i) {
            vbuf[g][h][0 * QPW + i] = oA[i];
            vbuf[g][h][1 * QPW + i] = oB[i];
            vbuf[g][h][2 * QPW + i] = aA[i];
            vbuf[g][h][3 * QPW + i] = aB[i];
            vbuf[g][h][4 * QPW + i] = mm[i];
        }
    }
    __syncthreads();
    #pragma unroll
    for (int i = 0; i < QPW; ++i) {
        const float pA = vbuf[g][h ^ 1][0 * QPW + i];
        const float pB = vbuf[g][h ^ 1][1 * QPW + i];
        float mn = fminf(oA[i], pA);
        oA[i] = fmaxf(oA[i], pA);
        oB[i] = fmaxf(mn, fmaxf(oB[i], pB));
        const float rA = vbuf[g][h ^ 1][2 * QPW + i];
        const float rB = vbuf[g][h ^ 1][3 * QPW + i];
        mn = fminf(aA[i], rA);
        aA[i] = fmaxf(aA[i], rA);
        aB[i] = fmaxf(mn, fmaxf(aB[i], rB));
        mm[i] = fmaxf(mm[i], vbuf[g][h ^ 1][4 * QPW + i]);
    }

    // recover indices on merged values (wave-wide ballot over OWN partials;
    // -1 if the winner came from the other half), publish via LDS.
    int jo0[QPW], jo1[QPW], ja0[QPW], ja1[QPW], jm[QPW];
    #pragma unroll
    for (int i = 0; i < QPW; ++i) {
        jo0[i] = recover_j(oA[i], soA[i], soB[i]);
        jo1[i] = recover_j(oB[i], soA[i], soB[i]);
        ja0[i] = recover_j(aA[i], saA[i], saB[i]);
        ja1[i] = recover_j(aB[i], saA[i], saB[i]);
        jm[i]  = recover_j(mm[i], sm[i], sm[i]);
    }
    if (ch == 0) {
        #pragma unroll
        for (int i = 0; i < QPW; ++i) {
            jbuf[g][h][0 * QPW + i] = jo0[i];
            jbuf[g][h][1 * QPW + i] = jo1[i];
            jbuf[g][h][2 * QPW + i] = ja0[i];
            jbuf[g][h][3 * QPW + i] = ja1[i];
            jbuf[g][h][4 * QPW + i] = jm[i];
        }
    }
    __syncthreads();

    float val = 0.0f;
    if (h == 0 && ch < QPW) {           // lane i of half-0 wave -> query qb+i
        auto pick = [&](int arr) {
            const int j0 = jbuf[g][0][arr * QPW + ch];
            const int j1 = jbuf[g][1][arr * QPW + ch];
            return j0 > j1 ? j0 : j1;   // exactly one is >= 0
        };
        const int io0 = pick(0), io1 = pick(1);
        const int ia0 = pick(2), ia1 = pick(3);
        const int im  = pick(4);
        const int q   = qb + ch;
        const float4 qoS = ob[q];
        const float4 qaS = ab[q];

        const float nx = nb[3 * q], ny = nb[3 * q + 1], nz = nb[3 * q + 2];
        const float ok = 0.5f * (unit_absdot4(ob, io0, qoS.x, qoS.y, qoS.z, nx, ny, nz) +
                                 unit_absdot4(ob, io1, qoS.x, qoS.y, qoS.z, nx, ny, nz));
        const float ax = nb[3 * im], ay = nb[3 * im + 1], az = nb[3 * im + 2];
        const float ak = 0.5f * (unit_absdot4(ab, ia0, qaS.x, qaS.y, qaS.z, ax, ay, az) +
                                 unit_absdot4(ab, ia1, qaS.x, qaS.y, qaS.z, ax, ay, az));
        const float d = ak - ok;
        val = d * d;
    }
    val += __shfl_down(val, 2);         // lanes 0..3 -> lane 0
    val += __shfl_down(val, 1);

    __shared__ float sval[GPB];
    if (h == 0 && ch == 0) sval[g] = val;
    __syncthreads();
    if (tid == 0) {
        const float s = sval[0] + sval[1];
        if (use_partial) partial[blockIdx.x] = s;
        else             atomicAdd(out, s * (1.0f / (float)(BB * NN)));
    }
}

__global__ __launch_bounds__(256) void reduce_kernel(
    const float* __restrict__ partial, float* __restrict__ out)
{
    const int tid = threadIdx.x;
    float s = 0.0f;
    #pragma unroll
    for (int i = tid; i < NBLK; i += 256) s += partial[i];
    #pragma unroll
    for (int off = 32; off > 0; off >>= 1) s += __shfl_down(s, off);
    __shared__ float ls[4];
    if ((tid & 63) == 0) ls[tid >> 6] = s;
    __syncthreads();
    if (tid == 0)
        out[0] = (ls[0] + ls[1] + ls[2] + ls[3]) * (1.0f / (float)(BB * NN));
}

extern "C" void kernel_launch(void* const* d_in, const int* in_sizes, int n_in,
                              void* d_out, int out_size, void* d_ws, size_t ws_size,
                              hipStream_t stream) {
    const float* ori = (const float*)d_in[0];
    const float* adv = (const float*)d_in[1];
    const float* nrm = (const float*)d_in[2];
    float* out = (float*)d_out;

    float4* oriP = (float4*)d_ws;                    // 256 KB
    float4* advP = oriP + (size_t)BB * NN;           // 256 KB
    float*  part = (float*)(advP + (size_t)BB * NN); // 8 KB
    const size_t need = (size_t)2 * BB * NN * sizeof(float4) + NBLK * sizeof(float);
    const int use_partial = (ws_size >= need) ? 1 : 0;

    if (!use_partial)
        hipMemsetAsync(out, 0, sizeof(float), stream);

    hipLaunchKernelGGL(pack_kernel, dim3((BB * NN + 255) / 256), dim3(256), 0, stream,
                       ori, adv, oriP, advP);
    hipLaunchKernelGGL(knn_kernel, dim3(NBLK), dim3(256), 0, stream,
                       oriP, advP, nrm, part, out, use_partial);
    if (use_partial)
        hipLaunchKernelGGL(reduce_kernel, dim3(1), dim3(256), 0, stream, part, out);
}

// Round 5
// 111.317 us; speedup vs baseline: 1.4119x; 1.0034x over previous
//
#include <hip/hip_runtime.h>

// CurvatureLoss: B=4, N=4096, fp32.
// R12: R9/R10/R11 showed every structure that raises VGPR to 64 loses ~16pt
// VALUBusy (tail stops hiding) and eats the QPW=4 instruction savings. Only
// the R7 envelope (QPW=2, VGPR=32, 2048x256 blocks) issues at 96%. So: R7
// verbatim + the one cut that fits inside it -- top-3 -> top-2 trackers with
// explicit self-zap (4 cndmask on the single wave-uniform self step) and no
// post-loop collapse. Saves ~10% of per-step ops, FREES 4 VGPRs (envelope
// preserved). Everything else (prefetch dist 2, embed6, ballot recovery,
// butterfly, epilogue) identical to the proven 51.6us kernel.

constexpr int BB   = 4;
constexpr int NN   = 4096;
constexpr int QPB  = 8;              // queries per block (4 waves x 2)
constexpr int CPB  = 64;             // chunk = lane
constexpr int NK   = NN / CPB;       // 64 steps; candidate j = 64*k + lane
constexpr int NBLK = BB * NN / QPB;  // 2048 blocks
constexpr float NEGBIG = -3.402823466e+38f;

__global__ __launch_bounds__(256) void pack_kernel(
    const float* __restrict__ ori, const float* __restrict__ adv,
    float4* __restrict__ oriP, float4* __restrict__ advP)
{
    const int i = blockIdx.x * blockDim.x + threadIdx.x;
    if (i < BB * NN) {
        float x = ori[3 * i], y = ori[3 * i + 1], z = ori[3 * i + 2];
        oriP[i] = make_float4(x, y, z, 0.5f * (x * x + y * y + z * z));
        x = adv[3 * i]; y = adv[3 * i + 1]; z = adv[3 * i + 2];
        advP[i] = make_float4(x, y, z, 0.5f * (x * x + y * y + z * z));
    }
}

__device__ __forceinline__ float embed6(float t, unsigned eb) {
    return __uint_as_float((__float_as_uint(t) & 0xFFFFFFC0u) | eb);  // v_and_or_b32
}

__device__ __forceinline__ float fmed3(float a, float b, float c) {
    return __builtin_amdgcn_fmed3f(a, b, c);
}

// v: merged key; p0/p1: this lane's partials. Wave-uniform.
// Lowest matching lane = smallest global index (j = 64k + lane).
__device__ __forceinline__ int recover_j(float v, float p0, float p1) {
    unsigned long long m = __ballot((p0 == v) || (p1 == v));
    const int lane = (int)__ffsll(m) - 1;
    const int k = (NK - 1) - (int)(__float_as_uint(v) & (unsigned)(NK - 1));
    return (k << 6) | lane;
}

__device__ __forceinline__ float unit_absdot4(const float4* __restrict__ pc, int i,
                                              float px, float py, float pz,
                                              float nx, float ny, float nz) {
    const float4 c = pc[i];
    const float vx = c.x - px, vy = c.y - py, vz = c.z - pz;
    const float s  = vx * vx + vy * vy + vz * vz + 1e-12f;
    return fabsf((vx * nx + vy * ny + vz * nz) * (1.0f / sqrtf(s)));
}

__global__ __launch_bounds__(256, 8) void knn_kernel(
    const float4* __restrict__ oriP, const float4* __restrict__ advP,
    const float* __restrict__ nrm, float* __restrict__ partial,
    float* __restrict__ out, int use_partial)
{
    const int tid = threadIdx.x;
    const int ch  = tid & 63;          // chunk = lane
    const int qs  = tid >> 6;          // wave id 0..3
    const int b   = blockIdx.x >> 9;   // / (N/QPB = 512)
    const int qt  = blockIdx.x & 511;
    const int q0  = qt * QPB + qs * 2;
    const int q1  = q0 + 1;

    const float4* __restrict__ ob = oriP + (size_t)b * NN;
    const float4* __restrict__ ab = advP + (size_t)b * NN;
    const float*  __restrict__ nb = nrm  + (size_t)b * NN * 3;

    const float4 qo0 = ob[q0], qo1 = ob[q1];
    const float4 qa0 = ab[q0], qa1 = ab[q1];

    // top-2 trackers (max = closest); self is zapped at its (uniform) step.
    float oA0 = NEGBIG, oB0 = NEGBIG;   // q0 ori-ori
    float oA1 = NEGBIG, oB1 = NEGBIG;   // q1 ori-ori
    float aA0 = NEGBIG, aB0 = NEGBIG;   // q0 adv-adv
    float aA1 = NEGBIG, aB1 = NEGBIG;   // q1 adv-adv
    float m0  = NEGBIG, m1  = NEGBIG;   // adv->ori argmax

    const int kself = q0 >> 6;          // q0,q1 share one self step (q0 even)
    const int s0l   = q0 & 63;          // self lane for q0; q1 is s0l+1

    const float4* __restrict__ op = ob + ch;
    const float4* __restrict__ ap = ab + ch;

    // one step of the key/selection body
    auto stepf = [&](const float4& co, const float4& ca, unsigned eb, bool selfstep) {
        float t;
        t = fmaf(qo0.z, co.z, -co.w); t = fmaf(qo0.y, co.y, t); t = fmaf(qo0.x, co.x, t);
        float ko0 = embed6(t, eb);
        t = fmaf(qo1.z, co.z, -co.w); t = fmaf(qo1.y, co.y, t); t = fmaf(qo1.x, co.x, t);
        float ko1 = embed6(t, eb);
        t = fmaf(qa0.z, co.z, -co.w); t = fmaf(qa0.y, co.y, t); t = fmaf(qa0.x, co.x, t);
        const float km0 = embed6(t, eb);
        t = fmaf(qa1.z, co.z, -co.w); t = fmaf(qa1.y, co.y, t); t = fmaf(qa1.x, co.x, t);
        const float km1 = embed6(t, eb);
        t = fmaf(qa0.z, ca.z, -ca.w); t = fmaf(qa0.y, ca.y, t); t = fmaf(qa0.x, ca.x, t);
        float ka0 = embed6(t, eb);
        t = fmaf(qa1.z, ca.z, -ca.w); t = fmaf(qa1.y, ca.y, t); t = fmaf(qa1.x, ca.x, t);
        float ka1 = embed6(t, eb);

        if (selfstep) {                 // wave-uniform, taken once in 64 steps
            const bool sq0 = (ch == s0l);
            const bool sq1 = (ch == s0l + 1);
            ko0 = sq0 ? NEGBIG : ko0;   // self excluded from ori-ori
            ka0 = sq0 ? NEGBIG : ka0;   // self excluded from adv-adv
            ko1 = sq1 ? NEGBIG : ko1;
            ka1 = sq1 ? NEGBIG : ka1;
            // km keeps self: ref argmin (adv->ori) is over ALL ori points
        }

        // top-2 update from OLD values (2-wide ILP):
        oB0 = fmed3(oA0, oB0, ko0); oA0 = fmaxf(oA0, ko0);
        oB1 = fmed3(oA1, oB1, ko1); oA1 = fmaxf(oA1, ko1);
        aB0 = fmed3(aA0, aB0, ka0); aA0 = fmaxf(aA0, ka0);
        aB1 = fmed3(aA1, aB1, ka1); aA1 = fmaxf(aA1, ka1);
        m0  = fmaxf(m0, km0);
        m1  = fmaxf(m1, km1);
    };

    // software pipeline, prefetch distance 2; rotations become renames
    // under unroll 2; last 2 steps peeled (no OOB prefetch).
    float4 c0o = op[0 * CPB], c0a = ap[0 * CPB];
    float4 c1o = op[1 * CPB], c1a = ap[1 * CPB];

    #pragma unroll 2
    for (int k = 0; k < NK - 2; ++k) {
        const float4 c2o = op[(k + 2) * CPB];
        const float4 c2a = ap[(k + 2) * CPB];
        stepf(c0o, c0a, (unsigned)(NK - 1 - k), k == kself);
        c0o = c1o; c0a = c1a;
        c1o = c2o; c1a = c2a;
    }
    stepf(c0o, c0a, 1u, (NK - 2) == kself);
    stepf(c1o, c1a, 0u, (NK - 1) == kself);

    // save per-lane partials for index recovery
    const float soA0 = oA0, soB0 = oB0, soA1 = oA1, soB1 = oB1;
    const float saA0 = aA0, saB0 = aB0, saA1 = aA1, saB1 = aB1;
    const float sm0 = m0, sm1 = m1;

    // wave butterfly top-2 merge: m0=max(a0,b0); m1=max(min(a0,b0),max(a1,b1))
    #pragma unroll
    for (int off = 1; off < 64; off <<= 1) {
        float r0, r1, mn;
        r0 = __shfl_xor(oA0, off); r1 = __shfl_xor(oB0, off);
        mn = fminf(oA0, r0); oA0 = fmaxf(oA0, r0); oB0 = fmaxf(mn, fmaxf(oB0, r1));
        r0 = __shfl_xor(oA1, off); r1 = __shfl_xor(oB1, off);
        mn = fminf(oA1, r0); oA1 = fmaxf(oA1, r0); oB1 = fmaxf(mn, fmaxf(oB1, r1));
        r0 = __shfl_xor(aA0, off); r1 = __shfl_xor(aB0, off);
        mn = fminf(aA0, r0); aA0 = fmaxf(aA0, r0); aB0 = fmaxf(mn, fmaxf(aB0, r1));
        r0 = __shfl_xor(aA1, off); r1 = __shfl_xor(aB1, off);
        mn = fminf(aA1, r0); aA1 = fmaxf(aA1, r0); aB1 = fmaxf(mn, fmaxf(aB1, r1));
        m0 = fmaxf(m0, __shfl_xor(m0, off));
        m1 = fmaxf(m1, __shfl_xor(m1, off));
    }

    // recover global candidate indices (wave-uniform)
    const int jo0_0 = recover_j(oA0, soA0, soB0);
    const int jo1_0 = recover_j(oB0, soA0, soB0);
    const int jo0_1 = recover_j(oA1, soA1, soB1);
    const int jo1_1 = recover_j(oB1, soA1, soB1);
    const int ja0_0 = recover_j(aA0, saA0, saB0);
    const int ja1_0 = recover_j(aB0, saA0, saB0);
    const int ja0_1 = recover_j(aA1, saA1, saB1);
    const int ja1_1 = recover_j(aB1, saA1, saB1);
    const int jm_0  = recover_j(m0, sm0, sm0);
    const int jm_1  = recover_j(m1, sm1, sm1);

    float val = 0.0f;
    if (ch < 2) {                       // lane0 -> q0, lane1 -> q1
        const int    q  = ch ? q1 : q0;
        const float4 qo = ch ? qo1 : qo0;
        const float4 qa = ch ? qa1 : qa0;
        const int io0 = ch ? jo0_1 : jo0_0;
        const int io1 = ch ? jo1_1 : jo1_0;
        const int ia0 = ch ? ja0_1 : ja0_0;
        const int ia1 = ch ? ja1_1 : ja1_0;
        const int im  = ch ? jm_1  : jm_0;

        const float nx = nb[3 * q], ny = nb[3 * q + 1], nz = nb[3 * q + 2];
        const float ok = 0.5f * (unit_absdot4(ob, io0, qo.x, qo.y, qo.z, nx, ny, nz) +
                                 unit_absdot4(ob, io1, qo.x, qo.y, qo.z, nx, ny, nz));
        const float ax = nb[3 * im], ay = nb[3 * im + 1], az = nb[3 * im + 2];
        const float ak = 0.5f * (unit_absdot4(ab, ia0, qa.x, qa.y, qa.z, ax, ay, az) +
                                 unit_absdot4(ab, ia1, qa.x, qa.y, qa.z, ax, ay, az));
        const float d = ak - ok;
        val = d * d;
    }
    val += __shfl_down(val, 1);         // lane0: q0 + q1

    __shared__ float sval[4];
    if (ch == 0) sval[qs] = val;
    __syncthreads();
    if (tid == 0) {
        const float s = sval[0] + sval[1] + sval[2] + sval[3];
        if (use_partial) partial[blockIdx.x] = s;
        else             atomicAdd(out, s * (1.0f / (float)(BB * NN)));
    }
}

__global__ __launch_bounds__(256) void reduce_kernel(
    const float* __restrict__ partial, float* __restrict__ out)
{
    const int tid = threadIdx.x;
    float s = 0.0f;
    #pragma unroll
    for (int i = tid; i < NBLK; i += 256) s += partial[i];
    #pragma unroll
    for (int off = 32; off > 0; off >>= 1) s += __shfl_down(s, off);
    __shared__ float ls[4];
    if ((tid & 63) == 0) ls[tid >> 6] = s;
    __syncthreads();
    if (tid == 0)
        out[0] = (ls[0] + ls[1] + ls[2] + ls[3]) * (1.0f / (float)(BB * NN));
}

extern "C" void kernel_launch(void* const* d_in, const int* in_sizes, int n_in,
                              void* d_out, int out_size, void* d_ws, size_t ws_size,
                              hipStream_t stream) {
    const float* ori = (const float*)d_in[0];
    const float* adv = (const float*)d_in[1];
    const float* nrm = (const float*)d_in[2];
    float* out = (float*)d_out;

    float4* oriP = (float4*)d_ws;                    // 256 KB
    float4* advP = oriP + (size_t)BB * NN;           // 256 KB
    float*  part = (float*)(advP + (size_t)BB * NN); // 8 KB
    const size_t need = (size_t)2 * BB * NN * sizeof(float4) + NBLK * sizeof(float);
    const int use_partial = (ws_size >= need) ? 1 : 0;

    if (!use_partial)
        hipMemsetAsync(out, 0, sizeof(float), stream);

    hipLaunchKernelGGL(pack_kernel, dim3((BB * NN + 255) / 256), dim3(256), 0, stream,
                       ori, adv, oriP, advP);
    hipLaunchKernelGGL(knn_kernel, dim3(NBLK), dim3(256), 0, stream,
                       oriP, advP, nrm, part, out, use_partial);
    if (use_partial)
        hipLaunchKernelGGL(reduce_kernel, dim3(1), dim3(256), 0, stream, part, out);
}

// Round 6
// 104.528 us; speedup vs baseline: 1.5036x; 1.0649x over previous
//
#include <hip/hip_runtime.h>

// CurvatureLoss: B=4, N=4096, fp32.
// R13: R12's in-loop selfstep branch caused scratch (WRITE 10.3MB) -> revert
// to R7's proven body (top-3 + post-collapse, no in-loop branches). New lever:
// total-knn gap is constant ~50us, so only knn matters; knn sits at 2-3x both
// the VALU floor (~16us) and the L1 model (~27us) while inst cuts never move
// time -> exposed L2 latency under a 2-deep pipeline + 4x redundant per-wave
// fetches. Fix: phase-staged LDS candidates via global_load_lds (4 steps/
// phase, double buffer, 16KB LDS, wave qs DMAs step qs of next phase), one
// __syncthreads per phase (implicit vmcnt drain = buffer-ready wait, issued a
// full phase earlier). Inner loads -> 2x ds_read_b128 with imm offsets.

constexpr int BB   = 4;
constexpr int NN   = 4096;
constexpr int QPB  = 8;              // queries per block (4 waves x 2)
constexpr int CPB  = 64;             // chunk = lane
constexpr int NK   = NN / CPB;       // 64 steps; candidate j = 64*k + lane
constexpr int PP   = 4;              // steps per phase (= waves per block)
constexpr int NP   = NK / PP;        // 16 phases
constexpr int NBLK = BB * NN / QPB;  // 2048 blocks
constexpr float NEGBIG = -3.402823466e+38f;

__global__ __launch_bounds__(256) void pack_kernel(
    const float* __restrict__ ori, const float* __restrict__ adv,
    float4* __restrict__ oriP, float4* __restrict__ advP)
{
    const int i = blockIdx.x * blockDim.x + threadIdx.x;
    if (i < BB * NN) {
        float x = ori[3 * i], y = ori[3 * i + 1], z = ori[3 * i + 2];
        oriP[i] = make_float4(x, y, z, 0.5f * (x * x + y * y + z * z));
        x = adv[3 * i]; y = adv[3 * i + 1]; z = adv[3 * i + 2];
        advP[i] = make_float4(x, y, z, 0.5f * (x * x + y * y + z * z));
    }
}

__device__ __forceinline__ float embed6(float t, unsigned eb) {
    return __uint_as_float((__float_as_uint(t) & 0xFFFFFFC0u) | eb);  // v_and_or_b32
}

__device__ __forceinline__ float fmed3(float a, float b, float c) {
    return __builtin_amdgcn_fmed3f(a, b, c);
}

// async global->LDS DMA, 16B per lane; lds dest = wave-uniform base + lane*16
__device__ __forceinline__ void async_copy16(const float4* g, float4* l) {
    __builtin_amdgcn_global_load_lds(
        (const __attribute__((address_space(1))) void*)g,
        (__attribute__((address_space(3))) void*)l, 16, 0, 0);
}

// v: merged key; p0/p1: this lane's (post-collapse) partials. Wave-uniform.
// Lowest matching lane = smallest global index (j = 64k + lane).
__device__ __forceinline__ int recover_j(float v, float p0, float p1) {
    unsigned long long m = __ballot((p0 == v) || (p1 == v));
    const int lane = (int)__ffsll(m) - 1;
    const int k = (NK - 1) - (int)(__float_as_uint(v) & (unsigned)(NK - 1));
    return (k << 6) | lane;
}

__device__ __forceinline__ float unit_absdot4(const float4* __restrict__ pc, int i,
                                              float px, float py, float pz,
                                              float nx, float ny, float nz) {
    const float4 c = pc[i];
    const float vx = c.x - px, vy = c.y - py, vz = c.z - pz;
    const float s  = vx * vx + vy * vy + vz * vz + 1e-12f;
    return fabsf((vx * nx + vy * ny + vz * nz) * (1.0f / sqrtf(s)));
}

__global__ __launch_bounds__(256, 8) void knn_kernel(
    const float4* __restrict__ oriP, const float4* __restrict__ advP,
    const float* __restrict__ nrm, float* __restrict__ partial,
    float* __restrict__ out, int use_partial)
{
    const int tid = threadIdx.x;
    const int ch  = tid & 63;          // chunk = lane
    const int qs  = tid >> 6;          // wave id 0..3
    const int b   = blockIdx.x >> 9;   // / (N/QPB = 512)
    const int qt  = blockIdx.x & 511;
    const int q0  = qt * QPB + qs * 2;
    const int q1  = q0 + 1;

    const float4* __restrict__ ob = oriP + (size_t)b * NN;
    const float4* __restrict__ ab = advP + (size_t)b * NN;
    const float*  __restrict__ nb = nrm  + (size_t)b * NN * 3;

    const float4 qo0 = ob[q0], qo1 = ob[q1];
    const float4 qa0 = ab[q0], qa1 = ab[q1];

    // top-3 trackers (max = closest); self key is guaranteed rank-1.
    float oA0 = NEGBIG, oB0 = NEGBIG, oC0 = NEGBIG;   // q0 ori-ori
    float oA1 = NEGBIG, oB1 = NEGBIG, oC1 = NEGBIG;   // q1 ori-ori
    float aA0 = NEGBIG, aB0 = NEGBIG, aC0 = NEGBIG;   // q0 adv-adv
    float aA1 = NEGBIG, aB1 = NEGBIG, aC1 = NEGBIG;   // q1 adv-adv
    float m0  = NEGBIG, m1  = NEGBIG;                 // adv->ori argmax

    // phase-staged candidate buffers: [buf][step-in-phase * 64 + cand]
    __shared__ float4 ldsO[2][PP * CPB];
    __shared__ float4 ldsA[2][PP * CPB];

    // wave qs stages step (ph*PP + qs) of phase ph into buffer bf.
    auto stage = [&](int ph, int bf) {
        const int k = ph * PP + qs;
        async_copy16(ob + (size_t)k * CPB + ch, &ldsO[bf][qs * CPB]);
        async_copy16(ab + (size_t)k * CPB + ch, &ldsA[bf][qs * CPB]);
    };

    // one step of the key/selection body (identical math to R7)
    auto stepf = [&](const float4& co, const float4& ca, unsigned eb) {
        float t;
        t = fmaf(qo0.z, co.z, -co.w); t = fmaf(qo0.y, co.y, t); t = fmaf(qo0.x, co.x, t);
        const float ko0 = embed6(t, eb);
        t = fmaf(qo1.z, co.z, -co.w); t = fmaf(qo1.y, co.y, t); t = fmaf(qo1.x, co.x, t);
        const float ko1 = embed6(t, eb);
        t = fmaf(qa0.z, co.z, -co.w); t = fmaf(qa0.y, co.y, t); t = fmaf(qa0.x, co.x, t);
        const float km0 = embed6(t, eb);
        t = fmaf(qa1.z, co.z, -co.w); t = fmaf(qa1.y, co.y, t); t = fmaf(qa1.x, co.x, t);
        const float km1 = embed6(t, eb);
        t = fmaf(qa0.z, ca.z, -ca.w); t = fmaf(qa0.y, ca.y, t); t = fmaf(qa0.x, ca.x, t);
        const float ka0 = embed6(t, eb);
        t = fmaf(qa1.z, ca.z, -ca.w); t = fmaf(qa1.y, ca.y, t); t = fmaf(qa1.x, ca.x, t);
        const float ka1 = embed6(t, eb);

        // top-3 update, all from OLD values (3-wide ILP):
        oC0 = fmed3(oB0, oC0, ko0); oB0 = fmed3(oA0, oB0, ko0); oA0 = fmaxf(oA0, ko0);
        oC1 = fmed3(oB1, oC1, ko1); oB1 = fmed3(oA1, oB1, ko1); oA1 = fmaxf(oA1, ko1);
        aC0 = fmed3(aB0, aC0, ka0); aB0 = fmed3(aA0, aB0, ka0); aA0 = fmaxf(aA0, ka0);
        aC1 = fmed3(aB1, aC1, ka1); aB1 = fmed3(aA1, aB1, ka1); aA1 = fmaxf(aA1, ka1);
        m0  = fmaxf(m0, km0);
        m1  = fmaxf(m1, km1);
    };

    // prologue: stage phase 0, drain, go.
    stage(0, 0);
    __syncthreads();                   // drains own vmcnt -> buf0 ready

    int cur = 0;
    for (int ph = 0; ph < NP; ++ph) {
        if (ph + 1 < NP) stage(ph + 1, cur ^ 1);   // async, no VGPR results
        const int kb = ph * PP;
        #pragma unroll
        for (int s = 0; s < PP; ++s) {
            const float4 co = ldsO[cur][s * CPB + ch];
            const float4 ca = ldsA[cur][s * CPB + ch];
            stepf(co, ca, (unsigned)(NK - 1 - (kb + s)));
        }
        __syncthreads();               // publishes next buffer (vmcnt drain)
        cur ^= 1;
    }

    // collapse self (guaranteed lane rank-1 in the self lane): drop it, keep 2.
    const bool s0 = ((q0 & 63) == ch) && ((q0 >> 6) >= 0);  // lane match
    const bool sq0 = ((q0 & 63) == ch);
    const bool sq1 = ((q1 & 63) == ch);
    (void)s0;
    oA0 = sq0 ? oB0 : oA0;  oB0 = sq0 ? oC0 : oB0;
    aA0 = sq0 ? aB0 : aA0;  aB0 = sq0 ? aC0 : aB0;
    oA1 = sq1 ? oB1 : oA1;  oB1 = sq1 ? oC1 : oB1;
    aA1 = sq1 ? aB1 : aA1;  aB1 = sq1 ? aC1 : aB1;

    // save per-lane partials for index recovery
    const float soA0 = oA0, soB0 = oB0, soA1 = oA1, soB1 = oB1;
    const float saA0 = aA0, saB0 = aB0, saA1 = aA1, saB1 = aB1;
    const float sm0 = m0, sm1 = m1;

    // wave butterfly top-2 merge: m0=max(a0,b0); m1=max(min(a0,b0),max(a1,b1))
    #pragma unroll
    for (int off = 1; off < 64; off <<= 1) {
        float r0, r1, mn;
        r0 = __shfl_xor(oA0, off); r1 = __shfl_xor(oB0, off);
        mn = fminf(oA0, r0); oA0 = fmaxf(oA0, r0); oB0 = fmaxf(mn, fmaxf(oB0, r1));
        r0 = __shfl_xor(oA1, off); r1 = __shfl_xor(oB1, off);
        mn = fminf(oA1, r0); oA1 = fmaxf(oA1, r0); oB1 = fmaxf(mn, fmaxf(oB1, r1));
        r0 = __shfl_xor(aA0, off); r1 = __shfl_xor(aB0, off);
        mn = fminf(aA0, r0); aA0 = fmaxf(aA0, r0); aB0 = fmaxf(mn, fmaxf(aB0, r1));
        r0 = __shfl_xor(aA1, off); r1 = __shfl_xor(aB1, off);
        mn = fminf(aA1, r0); aA1 = fmaxf(aA1, r0); aB1 = fmaxf(mn, fmaxf(aB1, r1));
        m0 = fmaxf(m0, __shfl_xor(m0, off));
        m1 = fmaxf(m1, __shfl_xor(m1, off));
    }

    // recover global candidate indices (wave-uniform)
    const int jo0_0 = recover_j(oA0, soA0, soB0);
    const int jo1_0 = recover_j(oB0, soA0, soB0);
    const int jo0_1 = recover_j(oA1, soA1, soB1);
    const int jo1_1 = recover_j(oB1, soA1, soB1);
    const int ja0_0 = recover_j(aA0, saA0, saB0);
    const int ja1_0 = recover_j(aB0, saA0, saB0);
    const int ja0_1 = recover_j(aA1, saA1, saB1);
    const int ja1_1 = recover_j(aB1, saA1, saB1);
    const int jm_0  = recover_j(m0, sm0, sm0);
    const int jm_1  = recover_j(m1, sm1, sm1);

    float val = 0.0f;
    if (ch < 2) {                       // lane0 -> q0, lane1 -> q1
        const int    q  = ch ? q1 : q0;
        const float4 qo = ch ? qo1 : qo0;
        const float4 qa = ch ? qa1 : qa0;
        const int io0 = ch ? jo0_1 : jo0_0;
        const int io1 = ch ? jo1_1 : jo1_0;
        const int ia0 = ch ? ja0_1 : ja0_0;
        const int ia1 = ch ? ja1_1 : ja1_0;
        const int im  = ch ? jm_1  : jm_0;

        const float nx = nb[3 * q], ny = nb[3 * q + 1], nz = nb[3 * q + 2];
        const float ok = 0.5f * (unit_absdot4(ob, io0, qo.x, qo.y, qo.z, nx, ny, nz) +
                                 unit_absdot4(ob, io1, qo.x, qo.y, qo.z, nx, ny, nz));
        const float ax = nb[3 * im], ay = nb[3 * im + 1], az = nb[3 * im + 2];
        const float ak = 0.5f * (unit_absdot4(ab, ia0, qa.x, qa.y, qa.z, ax, ay, az) +
                                 unit_absdot4(ab, ia1, qa.x, qa.y, qa.z, ax, ay, az));
        const float d = ak - ok;
        val = d * d;
    }
    val += __shfl_down(val, 1);         // lane0: q0 + q1

    __shared__ float sval[4];
    if (ch == 0) sval[qs] = val;
    __syncthreads();
    if (tid == 0) {
        const float s = sval[0] + sval[1] + sval[2] + sval[3];
        if (use_partial) partial[blockIdx.x] = s;
        else             atomicAdd(out, s * (1.0f / (float)(BB * NN)));
    }
}

__global__ __launch_bounds__(256) void reduce_kernel(
    const float* __restrict__ partial, float* __restrict__ out)
{
    const int tid = threadIdx.x;
    float s = 0.0f;
    #pragma unroll
    for (int i = tid; i < NBLK; i += 256) s += partial[i];
    #pragma unroll
    for (int off = 32; off > 0; off >>= 1) s += __shfl_down(s, off);
    __shared__ float ls[4];
    if ((tid & 63) == 0) ls[tid >> 6] = s;
    __syncthreads();
    if (tid == 0)
        out[0] = (ls[0] + ls[1] + ls[2] + ls[3]) * (1.0f / (float)(BB * NN));
}

extern "C" void kernel_launch(void* const* d_in, const int* in_sizes, int n_in,
                              void* d_out, int out_size, void* d_ws, size_t ws_size,
                              hipStream_t stream) {
    const float* ori = (const float*)d_in[0];
    const float* adv = (const float*)d_in[1];
    const float* nrm = (const float*)d_in[2];
    float* out = (float*)d_out;

    float4* oriP = (float4*)d_ws;                    // 256 KB
    float4* advP = oriP + (size_t)BB * NN;           // 256 KB
    float*  part = (float*)(advP + (size_t)BB * NN); // 8 KB
    const size_t need = (size_t)2 * BB * NN * sizeof(float4) + NBLK * sizeof(float);
    const int use_partial = (ws_size >= need) ? 1 : 0;

    if (!use_partial)
        hipMemsetAsync(out, 0, sizeof(float), stream);

    hipLaunchKernelGGL(pack_kernel, dim3((BB * NN + 255) / 256), dim3(256), 0, stream,
                       ori, adv, oriP, advP);
    hipLaunchKernelGGL(knn_kernel, dim3(NBLK), dim3(256), 0, stream,
                       oriP, advP, nrm, part, out, use_partial);
    if (use_partial)
        hipLaunchKernelGGL(reduce_kernel, dim3(1), dim3(256), 0, stream, part, out);
}